// Round 24
// baseline (356.651 us; speedup 1.0000x reference)
//
#include <hip/hip_runtime.h>
#include <cmath>

// Problem constants
static constexpr int kB   = 16;
static constexpr int kC   = 64;
static constexpr int kH   = 160;
static constexpr int kW   = 192;
static constexpr int kN   = 1000;
static constexpr int kAFC = 16;
static constexpr int kS   = 96;
static constexpr int kNC  = 2;
static constexpr int kD   = kAFC * kH;     // 2560
static constexpr int kHW  = kH * kW;       // 30720
static constexpr int kNM1 = kN - 1;        // 999
static constexpr int kM   = kB * kN;       // 16000
static constexpr int kRP  = kNC + 3 + 3 * kS; // 293
static constexpr int kK2  = 2 * kD;        // 5120
static constexpr int kNP  = 1024;          // padded N
static constexpr int kNW  = 1792;          // wcomb rows: 1024 attnw + 384 W1 + 384 W2

// Internal feature ordering is d' = h*16 + a (h-major).
// Reassociation: head = attn@(baf@W1^T) + baf@W2^T.
// Merged GEMM: C = baf @ wcomb^T, wcomb = [attnw | W1 | W2].
// Round-22 lesson: the XCD-chunked decode (xcd owns a contiguous m-stripe,
// m fastest within) is what keeps baf HBM-read ~once; round-24 applies that
// decode to the 128x256 / 3-ring / 2-blocks-per-CU geometry (M padded 16384).

// d_out layout (floats)
static constexpr size_t OFF_RP   = 0;
static constexpr size_t OFF_ATTN = (size_t)kB * kN * kRP;
static constexpr size_t OFF_FEAT = OFF_ATTN + (size_t)kB * kN * kN;

// ws layout (bytes)
static constexpr size_t WB_BAF   = 0;                                    // bf16 [16000][2560]
static constexpr size_t WB_WCOMB = WB_BAF   + (size_t)kM * kD * 2;       // bf16 [1792][2560]
static constexpr size_t WB_ATTNB = WB_WCOMB + (size_t)kNW * kD * 2;      // bf16 [16][1024][1024]
static constexpr size_t WB_SCORE = WB_ATTNB + (size_t)kB * kNP * kNP * 2;// bf16 [16000][1000]
static constexpr size_t WB_P1T   = WB_SCORE + (size_t)kM * 1000 * 2;     // bf16 [16][384][1024]
static constexpr size_t WB_P2    = WB_P1T   + (size_t)kB * 384 * kNP * 2;// bf16 [16000][384]
static constexpr size_t WB_CNT   = WB_P2    + (size_t)kM * 384 * 2;      // int[160] mask-evidence slots

typedef __attribute__((ext_vector_type(8))) short bf16x8;
typedef __attribute__((ext_vector_type(4))) float f32x4;

static __device__ inline short f2bf(float f) {
  union { float f; unsigned u; } x; x.f = f;
  unsigned r = (x.u + 0x7FFFu + ((x.u >> 16) & 1u)) >> 16;
  return (short)r;
}
static __device__ inline float bf2f(short s) {
  union { unsigned u; float f; } x; x.u = ((unsigned)(unsigned short)s) << 16;
  return x.f;
}

#define GLOAD_LDS16(gp, lp) __builtin_amdgcn_global_load_lds( \
    (const __attribute__((address_space(1))) void*)(gp),      \
    (__attribute__((address_space(3))) void*)(lp), 16, 0, 0)

// ---------------- mask dtype detection (parallel, slot-based) ----------------
__global__ __launch_bounds__(256) void k_detect(const unsigned char* __restrict__ m,
                                                int* __restrict__ cnt) {
  __shared__ int c1, c23;
  if (threadIdx.x == 0) { c1 = 0; c23 = 0; }
  __syncthreads();
  int l1 = 0, l23 = 0;
  int total = (kN * kH) / 4;
  for (int g = blockIdx.x * 256 + threadIdx.x; g < total; g += gridDim.x * 256) {
    l1  += (m[4 * g + 1] != 0);
    l23 += (m[4 * g + 2] != 0) + (m[4 * g + 3] != 0);
  }
  if (l1)  atomicOr(&c1, 1);
  if (l23) atomicOr(&c23, 1);
  __syncthreads();
  if (threadIdx.x == 0) cnt[blockIdx.x] = (c1 ? 1 : 0) | (c23 ? 2 : 0);
}

// ---------------- 1x1 conv (fp32, float4 x 4 pixels/thread) -----------------
__global__ __launch_bounds__(256) void k_conv(const float* __restrict__ bf,
                                              const float* __restrict__ cw,
                                              const float* __restrict__ cb,
                                              float* __restrict__ feats) {
  __shared__ float w[kAFC * kC];
  __shared__ float bsh[kAFC];
  for (int i = threadIdx.x; i < kAFC * kC; i += 256) w[i] = cw[i];
  if (threadIdx.x < kAFC) bsh[threadIdx.x] = cb[threadIdx.x];
  __syncthreads();
  int idx = blockIdx.x * 256 + threadIdx.x;     // pixel-quad index
  if (idx >= kB * (kHW / 4)) return;
  int b = idx / (kHW / 4), p = (idx % (kHW / 4)) * 4;
  float acc[kAFC][4];
#pragma unroll
  for (int o = 0; o < kAFC; o++) {
    float bv = bsh[o];
    acc[o][0] = bv; acc[o][1] = bv; acc[o][2] = bv; acc[o][3] = bv;
  }
  const float* src = bf + (size_t)b * kC * kHW + p;
#pragma unroll 4
  for (int c = 0; c < kC; c++) {
    float4 v = *(const float4*)(src + (size_t)c * kHW);
#pragma unroll
    for (int o = 0; o < kAFC; o++) {
      float wc = w[o * kC + c];
      acc[o][0] = fmaf(v.x, wc, acc[o][0]);
      acc[o][1] = fmaf(v.y, wc, acc[o][1]);
      acc[o][2] = fmaf(v.z, wc, acc[o][2]);
      acc[o][3] = fmaf(v.w, wc, acc[o][3]);
    }
  }
  float* dst = feats + (size_t)b * kAFC * kHW + p;
#pragma unroll
  for (int o = 0; o < kAFC; o++)
    *(float4*)(dst + (size_t)o * kHW) =
        make_float4(acc[o][0], acc[o][1], acc[o][2], acc[o][3]);
}

// ---------------- gather rois -> baf (bf16, d'=h*16+a layout) ---------------
__global__ __launch_bounds__(256) void k_gather(const float* __restrict__ feats,
                                                const int* __restrict__ cut,
                                                const void* __restrict__ mask,
                                                const int* __restrict__ cnt,
                                                short* __restrict__ baf) {
  __shared__ float lf[kAFC * 193];   // pad 192->193 to rotate banks per a
  __shared__ int fsh;
  int tid = threadIdx.x;
  if (tid == 0) fsh = 0;
  int bid = blockIdx.x;
  int b = bid & 15, h = bid >> 4;
  const float* fbase = feats + (size_t)b * kAFC * kHW + (size_t)h * kW;
  for (int i = tid; i < kAFC * kW; i += 256) {
    int a = i / kW, x = i % kW;
    lf[a * 193 + x] = fbase[(size_t)a * kHW + x];
  }
  __syncthreads();                   // lf ready AND fsh initialized
  if (tid < 160) { int v = cnt[tid]; if (v) atomicOr(&fsh, v); }
  __syncthreads();
  int fv = fsh;
  int f = (fv & 1) ? 1 : ((fv & 2) ? 2 : 0);
  for (int n = tid; n < kN; n += 256) {
    int r = n * kH + h;
    bool inv;
    if (f == 0)      inv = ((const int*)mask)[r] != 0;
    else if (f == 1) inv = ((const unsigned char*)mask)[r] != 0;
    else             inv = ((const float*)mask)[r] != 0.0f;
    bf16x8 v0 = {}, v1 = {};
    if (!inv) {
      int x = cut[r];
#pragma unroll
      for (int a = 0; a < 8; a++)  v0[a] = f2bf(lf[a * 193 + x]);
#pragma unroll
      for (int a = 0; a < 8; a++)  v1[a] = f2bf(lf[(a + 8) * 193 + x]);
    }
    short* dst = baf + (size_t)(b * kN + n) * kD + h * kAFC;
    *(bf16x8*)dst = v0;
    *(bf16x8*)(dst + 8) = v1;
  }
}

// ---- build combined weight wcomb [1792][2560] in d' order ------------------
__global__ __launch_bounds__(256) void k_cvt_wcomb(const float* __restrict__ attn_w,
                                                   const float* __restrict__ reg_w,
                                                   const float* __restrict__ cls_w,
                                                   short* __restrict__ wcomb) {
  __shared__ float lw[2 * kAFC * (kH + 1)];  // 2 x 16 x 161
  int j = blockIdx.x;                        // 0..1407
  if (j < kNP) {
    short* dst = wcomb + (size_t)j * kD;
    if (j < kNM1) {
      const float* src = attn_w + (size_t)j * kD;
      for (int i = threadIdx.x; i < kD; i += 256) {
        int a = i / kH, h = i % kH;
        lw[a * (kH + 1) + h] = src[i];
      }
      __syncthreads();
      for (int dp = threadIdx.x; dp < kD; dp += 256) {
        int h = dp >> 4, a = dp & 15;
        dst[dp] = f2bf(lw[a * (kH + 1) + h]);
      }
    } else {
      for (int dp = threadIdx.x; dp < kD; dp += 256) dst[dp] = 0;
    }
  } else {
    int jp = j - kNP;                        // 0..383
    const float* src = nullptr;
    if (jp < 3 * kS)                src = reg_w + (size_t)jp * kK2;
    else if (jp < 3 * kS + kNC)     src = cls_w + (size_t)(jp - 3 * kS) * kK2;
    short* d0 = wcomb + (size_t)(kNP + jp) * kD;
    short* d1 = wcomb + (size_t)(kNP + 384 + jp) * kD;
    if (src) {
      for (int i = threadIdx.x; i < kK2; i += 256) {
        int half = i / kD, t = i % kD;
        int a = t / kH, h = t % kH;
        lw[(half * kAFC + a) * (kH + 1) + h] = src[i];
      }
      __syncthreads();
      for (int kp = threadIdx.x; kp < kD; kp += 256) {
        int h = kp >> 4, a = kp & 15;
        d0[kp] = f2bf(lw[a * (kH + 1) + h]);
        d1[kp] = f2bf(lw[(kAFC + a) * (kH + 1) + h]);
      }
    } else {
      for (int kp = threadIdx.x; kp < kD; kp += 256) { d0[kp] = 0; d1[kp] = 0; }
    }
  }
}

// ---------------- softmax: bf16 scores -> attn f32 out + attn bf16 padded ---
__global__ __launch_bounds__(256) void k_softmax(const short* __restrict__ scores,
                                                 const float* __restrict__ anchors,
                                                 float* __restrict__ attn_out,
                                                 short* __restrict__ attn_bf,
                                                 float* __restrict__ rp) {
  int m = blockIdx.x;           // 0..15999
  int b = m / kN;
  int i = m % kN;
  const short* srow = scores + (size_t)m * 1000;
  int tid = threadIdx.x;
  int j0 = tid * 4;
  __shared__ float red[4];
  float v[4];
  if (j0 < 1000) {
    short4 s4 = *(const short4*)(srow + j0);
    v[0] = bf2f(s4.x); v[1] = bf2f(s4.y); v[2] = bf2f(s4.z); v[3] = bf2f(s4.w);
  } else {
    v[0] = v[1] = v[2] = v[3] = -INFINITY;
  }
#pragma unroll
  for (int t = 0; t < 4; t++) if (j0 + t >= kNM1) v[t] = -INFINITY;
  float mx = fmaxf(fmaxf(v[0], v[1]), fmaxf(v[2], v[3]));
#pragma unroll
  for (int o = 32; o; o >>= 1) mx = fmaxf(mx, __shfl_down(mx, o));
  if ((tid & 63) == 0) red[tid >> 6] = mx;
  __syncthreads();
  mx = fmaxf(fmaxf(red[0], red[1]), fmaxf(red[2], red[3]));
  __syncthreads();
  float s = 0.f;
#pragma unroll
  for (int t = 0; t < 4; t++) {
    v[t] = (j0 + t < kNM1) ? __expf(v[t] - mx) : 0.f;
    s += v[t];
  }
#pragma unroll
  for (int o = 32; o; o >>= 1) s += __shfl_down(s, o);
  if ((tid & 63) == 0) red[tid >> 6] = s;
  __syncthreads();
  s = red[0] + red[1] + red[2] + red[3];
  float inv = 1.0f / s;
  float* orow = attn_out + (size_t)m * kN;
  short* brow = attn_bf + ((size_t)b * kNP + i) * kNP;
  if (j0 + 3 < i && j0 + 3 < kNM1) {
    float p0 = v[0] * inv, p1 = v[1] * inv, p2v = v[2] * inv, p3 = v[3] * inv;
    *(float4*)(orow + j0) = make_float4(p0, p1, p2v, p3);
    *(short4*)(brow + j0) = make_short4(f2bf(p0), f2bf(p1), f2bf(p2v), f2bf(p3));
  } else {
#pragma unroll
    for (int t = 0; t < 4; t++) {
      int j = j0 + t;
      if (j < kNM1) {
        int dst = j + (j >= i);
        float p = v[t] * inv;
        orow[dst] = p;
        brow[dst] = f2bf(p);
      }
    }
  }
  if (tid == 0) { orow[i] = 0.f; brow[i] = 0; }
  if (tid < kNP - kN) brow[kN + tid] = 0;           // pad cols 1000..1023
  if (tid < 3) rp[(size_t)m * kRP + 2 + tid] = anchors[(size_t)i * kRP + 2 + tid];
}

// ---------------- merged GEMM: C = baf @ wcomb^T, 128x256 tile --------------
// XCD-chunked decode (round-21 property) + 3-deep ring (3 x 24KB = 72KB ->
// 2 blocks/CU), vmcnt(3) steady. Grid 896 = 8 XCD x (16 m-tiles fastest x
// 7 n-tiles); M padded to 16384 via row clamp + guarded stores.
// Epilogue: n-tiles 0-3 -> scores; tile 4 + pass0 of 5 -> p1t (LDS
// transpose); rest of 5 + tile 6 -> p2 (direct).
__global__ __launch_bounds__(512, 4) void k_mgemm(
    const short* __restrict__ A,
    const short* __restrict__ Bt,     // wcomb [1792][2560]
    const float* __restrict__ bias,
    short* __restrict__ scores,
    short* __restrict__ p1t,
    short* __restrict__ p2) {
  extern __shared__ char dls[];                // 72 KB: 3 bufs x (A 8K + B 16K)
  constexpr int NT = kD / 32;                  // 80
  constexpr int BUFSZ = 24576;
  int tid = threadIdx.x, lane = tid & 63, wv = tid >> 6;
  int bid = blockIdx.x;
  int xcd = bid & 7, s = bid >> 3;             // s: 0..111
  int m0 = (xcd * 16 + (s & 15)) * 128;        // 0..16256 (M padded to 16384)
  int n0t = s >> 4;                            // 0..6
  int n0 = n0t * 256;
  int wm = (wv & 1) * 64, wn = (wv >> 1) * 64;
  f32x4 acc[4][4] = {};

  int swzko = (((tid & 3) ^ ((tid >> 3) & 3)) * 8);   // pre-swizzled k-offset
  int arow = min(m0 + (tid >> 2), kM - 1);
  const short* gA  = A + (size_t)arow * kD + swzko;
  const short* gB0 = Bt + (size_t)(n0 + (tid >> 2)) * kD + swzko;
  const short* gB1 = Bt + (size_t)(n0 + ((512 + tid) >> 2)) * kD + swzko;

  auto STAGE = [&](int tt) {
    char* buf = dls + (size_t)(tt % 3) * BUFSZ;
    int k0 = tt * 32;
    GLOAD_LDS16(gA + k0,  buf + wv * 1024);
    GLOAD_LDS16(gB0 + k0, buf + 8192 + wv * 1024);
    GLOAD_LDS16(gB1 + k0, buf + 16384 + wv * 1024);
  };

  int cswz = (((lane >> 4) ^ ((lane >> 1) & 3)) * 16); // swizzled read column

  STAGE(0); STAGE(1);
  for (int t = 0; t < NT; t++) {
    if (t < NT - 1) asm volatile("s_waitcnt vmcnt(3)" ::: "memory");
    else            asm volatile("s_waitcnt vmcnt(0)" ::: "memory");
    __builtin_amdgcn_s_barrier();
    __builtin_amdgcn_sched_barrier(0);
    if (t + 2 < NT) STAGE(t + 2);
    const char* bufA = dls + (size_t)(t % 3) * BUFSZ;
    const char* bufB = bufA + 8192;
    bf16x8 af[4], bg[4];
#pragma unroll
    for (int i = 0; i < 4; i++)
      af[i] = *(const bf16x8*)(bufA + (wm + i * 16 + (lane & 15)) * 64 + cswz);
#pragma unroll
    for (int j = 0; j < 4; j++)
      bg[j] = *(const bf16x8*)(bufB + (wn + j * 16 + (lane & 15)) * 64 + cswz);
    __builtin_amdgcn_s_setprio(1);
#pragma unroll
    for (int i = 0; i < 4; i++)
#pragma unroll
      for (int j = 0; j < 4; j++)
        acc[i][j] = __builtin_amdgcn_mfma_f32_16x16x32_bf16(af[i], bg[j], acc[i][j], 0, 0, 0);
    __builtin_amdgcn_s_setprio(0);
  }

  if (n0t < 4) {
    // scores region
#pragma unroll
    for (int i = 0; i < 4; i++) {
#pragma unroll
      for (int j = 0; j < 4; j++) {
#pragma unroll
        for (int r = 0; r < 4; r++) {
          int row = m0 + wm + i * 16 + (lane >> 4) * 4 + r;
          int col = n0 + wn + j * 16 + (lane & 15);
          if (row < kM && col < kNM1)
            scores[(size_t)row * 1000 + col] = f2bf(acc[i][j][r] + bias[col]);
        }
      }
    }
  } else {
    int base = n0 - 1024;              // w-space col offset: 0 / 256 / 512
    // direct p2 region: tile 6 all; tile 5 local cols >= 128 (jw >= 384)
    if (n0t >= 5) {
#pragma unroll
      for (int i = 0; i < 4; i++) {
#pragma unroll
        for (int j = 0; j < 4; j++) {
#pragma unroll
          for (int r = 0; r < 4; r++) {
            int row = m0 + wm + i * 16 + (lane >> 4) * 4 + r;
            int cl = wn + j * 16 + (lane & 15);
            int jw = base + cl;
            if (jw >= 384 && row < kM)
              p2[(size_t)row * 384 + (jw - 384)] = f2bf(acc[i][j][r]);
          }
        }
      }
    }
    // transpose region -> p1t: ONLY tiles 4 (both passes) and 5 (pass 0).
    if (n0t <= 5) {
      __syncthreads();                 // all waves' final ring ds_reads retired
      short* lds2 = (short*)dls;       // [128 cols][136]; stride 272B (16-aligned)
      int npass = (n0t == 4) ? 2 : 1;
      for (int pass = 0; pass < npass; pass++) {
        if ((wn < 128) == (pass == 0)) {
#pragma unroll
          for (int i = 0; i < 4; i++) {
#pragma unroll
            for (int j = 0; j < 4; j++) {
#pragma unroll
              for (int r = 0; r < 4; r++) {
                int rowl = wm + i * 16 + (lane >> 4) * 4 + r;      // 0..127
                int cl = (wn + j * 16 + (lane & 15)) - pass * 128; // 0..127
                lds2[cl * 136 + rowl] = f2bf(acc[i][j][r]);
              }
            }
          }
        }
        __syncthreads();
        for (int u = tid; u < 128 * 16; u += 512) {
          int c = u >> 4, oct = u & 15;
          int jw = base + pass * 128 + c;
          int grow = m0 + oct * 8;
          if (jw < 384 && grow < kM) {
            int b = grow / kN, n = grow - b * kN;
            *(bf16x8*)(p1t + ((size_t)b * 384 + jw) * kNP + n) =
                *(const bf16x8*)(lds2 + c * 136 + oct * 8);
          }
        }
        __syncthreads();
      }
    }
  }
}

// ---------------- F-GEMM: Y[b] = attn_bf[b] @ p1t[b]^T + p2 + epilogue ------
// BM=32, 512 blocks, 3-deep ring (78 KB -> 2 blocks/CU), vmcnt(4) steady.
__global__ __launch_bounds__(512, 2) void k_fgemm(
    const short* __restrict__ attn_bf,  // [16][1024][1024]
    const short* __restrict__ p1t,      // [16][384][1024]
    const short* __restrict__ p2,       // [16000][384]
    const float* __restrict__ reg_b, const float* __restrict__ cls_b,
    const float* __restrict__ anchors, float* __restrict__ rp) {
  extern __shared__ char dls[];      // 3 bufs x (A 2K + B 24K) = 78 KB
  constexpr int NT = kNP / 32;       // 32
  constexpr int BUFSZ = 26624;
  int tid = threadIdx.x, lane = tid & 63, wv = tid >> 6;
  int bid = blockIdx.x;
  int b = bid & 15, mt = bid >> 4;   // XCD = bid&7 -> b in {x, x+8}: p1t L2-hot
  int m0 = mt * 32;                  // mt 0..31
  const short* Ap = attn_bf + (size_t)b * kNP * kNP;
  const short* Bp = p1t + (size_t)b * 384 * kNP;

  int wm = (wv & 1) * 16, wn = (wv >> 1) * 96;
  f32x4 acc[6] = {};

  int ciA = tid & 127;
  int swzkoA = (((ciA & 3) ^ ((ciA >> 3) & 3)) * 8);
  int swzko  = (((tid & 3) ^ ((tid >> 3) & 3)) * 8);
  const short* gA  = Ap + (size_t)(m0 + (ciA >> 2)) * kNP + swzkoA;
  const short* gB0 = Bp + (size_t)(tid >> 2) * kNP + swzko;
  const short* gB1 = Bp + (size_t)((512 + tid) >> 2) * kNP + swzko;
  const short* gB2 = Bp + (size_t)((1024 + tid) >> 2) * kNP + swzko;

  auto STAGE = [&](int tt) {
    char* buf = dls + (size_t)(tt % 3) * BUFSZ;
    int k0 = tt * 32;
    GLOAD_LDS16(gA + k0,  buf + (wv & 1) * 1024);
    GLOAD_LDS16(gB0 + k0, buf + 2048 + wv * 1024);
    GLOAD_LDS16(gB1 + k0, buf + 10240 + wv * 1024);
    GLOAD_LDS16(gB2 + k0, buf + 18432 + wv * 1024);
  };

  int cswz = (((lane >> 4) ^ ((lane >> 1) & 3)) * 16);

  STAGE(0); STAGE(1);
  for (int t = 0; t < NT; t++) {
    if (t < NT - 1) asm volatile("s_waitcnt vmcnt(4)" ::: "memory");
    else            asm volatile("s_waitcnt vmcnt(0)" ::: "memory");
    __builtin_amdgcn_s_barrier();
    __builtin_amdgcn_sched_barrier(0);
    if (t + 2 < NT) STAGE(t + 2);
    const char* bufA = dls + (size_t)(t % 3) * BUFSZ;
    const char* bufB = bufA + 2048;
    bf16x8 af, bg[6];
    af = *(const bf16x8*)(bufA + (wm + (lane & 15)) * 64 + cswz);
#pragma unroll
    for (int j = 0; j < 6; j++)
      bg[j] = *(const bf16x8*)(bufB + (wn + j * 16 + (lane & 15)) * 64 + cswz);
    __builtin_amdgcn_s_setprio(1);
#pragma unroll
    for (int j = 0; j < 6; j++)
      acc[j] = __builtin_amdgcn_mfma_f32_16x16x32_bf16(af, bg[j], acc[j], 0, 0, 0);
    __builtin_amdgcn_s_setprio(0);
  }

#pragma unroll
  for (int j = 0; j < 6; j++) {
#pragma unroll
    for (int r = 0; r < 4; r++) {
      int n = m0 + wm + (lane >> 4) * 4 + r;            // 0..1023
      int col = wn + j * 16 + (lane & 15);              // 0..383
      if (n < kN) {
        size_t row = (size_t)b * kN + n;
        float v = acc[j][r] + bf2f(p2[row * 384 + col]);
        if (col < 3 * kS) {
          float tv = v + reg_b[col];
          if (col >= 2 * kS) tv = 1.0f / (1.0f + __expf(-tv));
          rp[row * kRP + 5 + col] = anchors[(size_t)n * kRP + 5 + col] + tv;
        } else if (col < 3 * kS + kNC) {
          rp[row * kRP + (col - 3 * kS)] = v + cls_b[col - 3 * kS];
        }
      }
    }
  }
}

extern "C" void kernel_launch(void* const* d_in, const int* in_sizes, int n_in,
                              void* d_out, int out_size, void* d_ws, size_t ws_size,
                              hipStream_t stream) {
  const float* bf      = (const float*)d_in[0];
  const float* conv_w  = (const float*)d_in[1];
  const float* conv_b  = (const float*)d_in[2];
  const int*   cut     = (const int*)d_in[3];
  const void*  mask    = d_in[4];
  const float* anchors = (const float*)d_in[5];
  const float* attn_w  = (const float*)d_in[6];
  const float* attn_b  = (const float*)d_in[7];
  const float* cls_w   = (const float*)d_in[8];
  const float* cls_b   = (const float*)d_in[9];
  const float* reg_w   = (const float*)d_in[10];
  const float* reg_b   = (const float*)d_in[11];

  float* out    = (float*)d_out;
  float* rp     = out + OFF_RP;
  float* attn_o = out + OFF_ATTN;
  float* feats  = out + OFF_FEAT;

  char*  ws      = (char*)d_ws;
  short* baf     = (short*)(ws + WB_BAF);
  short* wcomb   = (short*)(ws + WB_WCOMB);
  short* attn_bf = (short*)(ws + WB_ATTNB);
  short* scores  = (short*)(ws + WB_SCORE);
  short* p1t     = (short*)(ws + WB_P1T);
  short* p2      = (short*)(ws + WB_P2);
  int*   cnt     = (int*)(ws + WB_CNT);

  k_detect<<<160, 256, 0, stream>>>((const unsigned char*)mask, cnt);
  k_conv<<<(kB * kHW / 4 + 255) / 256, 256, 0, stream>>>(bf, conv_w, conv_b, feats);
  // gather: one block per (b,h); 2560 blocks
  k_gather<<<kB * kH, 256, 0, stream>>>(feats, cut, mask, cnt, baf);
  k_cvt_wcomb<<<kNP + 384, 256, 0, stream>>>(attn_w, reg_w, cls_w, wcomb);
  // merged GEMM: 896 blocks (8 XCD x 16 m-tiles fastest x 7 n), 72KB, 2/CU
  k_mgemm<<<896, 512, 73728, stream>>>(baf, wcomb, attn_b, scores, p1t, p2);
  k_softmax<<<kM, 256, 0, stream>>>(scores, anchors, attn_o, attn_bf, rp);
  // F-GEMM: 512 blocks (16 batches x 32 m-tiles), 2 blocks/CU
  k_fgemm<<<512, 512, 79872, stream>>>(attn_bf, p1t, p2, reg_b, cls_b,
                                       anchors, rp);
}

// Round 25
// 350.107 us; speedup vs baseline: 1.0187x; 1.0187x over previous
//
#include <hip/hip_runtime.h>
#include <cmath>

// Problem constants
static constexpr int kB   = 16;
static constexpr int kC   = 64;
static constexpr int kH   = 160;
static constexpr int kW   = 192;
static constexpr int kN   = 1000;
static constexpr int kAFC = 16;
static constexpr int kS   = 96;
static constexpr int kNC  = 2;
static constexpr int kD   = kAFC * kH;     // 2560
static constexpr int kHW  = kH * kW;       // 30720
static constexpr int kNM1 = kN - 1;        // 999
static constexpr int kM   = kB * kN;       // 16000
static constexpr int kRP  = kNC + 3 + 3 * kS; // 293
static constexpr int kK2  = 2 * kD;        // 5120
static constexpr int kNP  = 1024;          // padded N
static constexpr int kNW  = 1792;          // wcomb rows: 1024 attnw + 384 W1 + 384 W2

// Internal feature ordering is d' = h*16 + a (h-major); all internal tensors
// and repacked weights use d' consistently.
// Reassociation: head = attn@(baf@W1^T) + baf@W2^T.
// Merged GEMM: C = baf @ wcomb^T, wcomb = [attnw | W1 | W2].
// Mapping (rounds 22/24 lessons): XCD-chunked 256^2 tiles are a verified
// local optimum — 128-tile variants raise FETCH 116->191/333MB and regress
// despite 2x occupancy; the ring structure (38% MfmaUtil) is the binding
// constraint, addressable only by an 8-phase schedule port (not attempted
// headless per race-screen discipline).

// d_out layout (floats)
static constexpr size_t OFF_RP   = 0;
static constexpr size_t OFF_ATTN = (size_t)kB * kN * kRP;
static constexpr size_t OFF_FEAT = OFF_ATTN + (size_t)kB * kN * kN;

// ws layout (bytes)
static constexpr size_t WB_BAF   = 0;                                    // bf16 [16000][2560]
static constexpr size_t WB_WCOMB = WB_BAF   + (size_t)kM * kD * 2;       // bf16 [1792][2560]
static constexpr size_t WB_ATTNB = WB_WCOMB + (size_t)kNW * kD * 2;      // bf16 [16][1024][1024]
static constexpr size_t WB_SCORE = WB_ATTNB + (size_t)kB * kNP * kNP * 2;// bf16 [16000][1000]
static constexpr size_t WB_P1T   = WB_SCORE + (size_t)kM * 1000 * 2;     // bf16 [16][384][1024]
static constexpr size_t WB_P2    = WB_P1T   + (size_t)kB * 384 * kNP * 2;// bf16 [16000][384]
static constexpr size_t WB_CNT   = WB_P2    + (size_t)kM * 384 * 2;      // int[160] mask-evidence slots

typedef __attribute__((ext_vector_type(8))) short bf16x8;
typedef __attribute__((ext_vector_type(4))) float f32x4;

static __device__ inline short f2bf(float f) {
  union { float f; unsigned u; } x; x.f = f;
  unsigned r = (x.u + 0x7FFFu + ((x.u >> 16) & 1u)) >> 16;
  return (short)r;
}
static __device__ inline float bf2f(short s) {
  union { unsigned u; float f; } x; x.u = ((unsigned)(unsigned short)s) << 16;
  return x.f;
}

#define GLOAD_LDS16(gp, lp) __builtin_amdgcn_global_load_lds( \
    (const __attribute__((address_space(1))) void*)(gp),      \
    (__attribute__((address_space(3))) void*)(lp), 16, 0, 0)

// ---------------- mask dtype detection (parallel, slot-based) ----------------
__global__ __launch_bounds__(256) void k_detect(const unsigned char* __restrict__ m,
                                                int* __restrict__ cnt) {
  __shared__ int c1, c23;
  if (threadIdx.x == 0) { c1 = 0; c23 = 0; }
  __syncthreads();
  int l1 = 0, l23 = 0;
  int total = (kN * kH) / 4;
  for (int g = blockIdx.x * 256 + threadIdx.x; g < total; g += gridDim.x * 256) {
    l1  += (m[4 * g + 1] != 0);
    l23 += (m[4 * g + 2] != 0) + (m[4 * g + 3] != 0);
  }
  if (l1)  atomicOr(&c1, 1);
  if (l23) atomicOr(&c23, 1);
  __syncthreads();
  if (threadIdx.x == 0) cnt[blockIdx.x] = (c1 ? 1 : 0) | (c23 ? 2 : 0);
}

// ---------------- 1x1 conv (fp32, float4 x 4 pixels/thread) -----------------
__global__ __launch_bounds__(256) void k_conv(const float* __restrict__ bf,
                                              const float* __restrict__ cw,
                                              const float* __restrict__ cb,
                                              float* __restrict__ feats) {
  __shared__ float w[kAFC * kC];
  __shared__ float bsh[kAFC];
  for (int i = threadIdx.x; i < kAFC * kC; i += 256) w[i] = cw[i];
  if (threadIdx.x < kAFC) bsh[threadIdx.x] = cb[threadIdx.x];
  __syncthreads();
  int idx = blockIdx.x * 256 + threadIdx.x;     // pixel-quad index
  if (idx >= kB * (kHW / 4)) return;
  int b = idx / (kHW / 4), p = (idx % (kHW / 4)) * 4;
  float acc[kAFC][4];
#pragma unroll
  for (int o = 0; o < kAFC; o++) {
    float bv = bsh[o];
    acc[o][0] = bv; acc[o][1] = bv; acc[o][2] = bv; acc[o][3] = bv;
  }
  const float* src = bf + (size_t)b * kC * kHW + p;
#pragma unroll 4
  for (int c = 0; c < kC; c++) {
    float4 v = *(const float4*)(src + (size_t)c * kHW);
#pragma unroll
    for (int o = 0; o < kAFC; o++) {
      float wc = w[o * kC + c];
      acc[o][0] = fmaf(v.x, wc, acc[o][0]);
      acc[o][1] = fmaf(v.y, wc, acc[o][1]);
      acc[o][2] = fmaf(v.z, wc, acc[o][2]);
      acc[o][3] = fmaf(v.w, wc, acc[o][3]);
    }
  }
  float* dst = feats + (size_t)b * kAFC * kHW + p;
#pragma unroll
  for (int o = 0; o < kAFC; o++)
    *(float4*)(dst + (size_t)o * kHW) =
        make_float4(acc[o][0], acc[o][1], acc[o][2], acc[o][3]);
}

// ---------------- gather rois -> baf (bf16, d'=h*16+a layout) ---------------
__global__ __launch_bounds__(256) void k_gather(const float* __restrict__ feats,
                                                const int* __restrict__ cut,
                                                const void* __restrict__ mask,
                                                const int* __restrict__ cnt,
                                                short* __restrict__ baf) {
  __shared__ float lf[kAFC * 193];   // pad 192->193 to rotate banks per a
  __shared__ int fsh;
  int tid = threadIdx.x;
  if (tid == 0) fsh = 0;
  int bid = blockIdx.x;
  int b = bid & 15, h = bid >> 4;
  const float* fbase = feats + (size_t)b * kAFC * kHW + (size_t)h * kW;
  for (int i = tid; i < kAFC * kW; i += 256) {
    int a = i / kW, x = i % kW;
    lf[a * 193 + x] = fbase[(size_t)a * kHW + x];
  }
  __syncthreads();                   // lf ready AND fsh initialized
  if (tid < 160) { int v = cnt[tid]; if (v) atomicOr(&fsh, v); }
  __syncthreads();
  int fv = fsh;
  int f = (fv & 1) ? 1 : ((fv & 2) ? 2 : 0);
  for (int n = tid; n < kN; n += 256) {
    int r = n * kH + h;
    bool inv;
    if (f == 0)      inv = ((const int*)mask)[r] != 0;
    else if (f == 1) inv = ((const unsigned char*)mask)[r] != 0;
    else             inv = ((const float*)mask)[r] != 0.0f;
    bf16x8 v0 = {}, v1 = {};
    if (!inv) {
      int x = cut[r];
#pragma unroll
      for (int a = 0; a < 8; a++)  v0[a] = f2bf(lf[a * 193 + x]);
#pragma unroll
      for (int a = 0; a < 8; a++)  v1[a] = f2bf(lf[(a + 8) * 193 + x]);
    }
    short* dst = baf + (size_t)(b * kN + n) * kD + h * kAFC;
    *(bf16x8*)dst = v0;
    *(bf16x8*)(dst + 8) = v1;
  }
}

// ---- build combined weight wcomb [1792][2560] in d' order ------------------
__global__ __launch_bounds__(256) void k_cvt_wcomb(const float* __restrict__ attn_w,
                                                   const float* __restrict__ reg_w,
                                                   const float* __restrict__ cls_w,
                                                   short* __restrict__ wcomb) {
  __shared__ float lw[2 * kAFC * (kH + 1)];  // 2 x 16 x 161
  int j = blockIdx.x;                        // 0..1407
  if (j < kNP) {
    short* dst = wcomb + (size_t)j * kD;
    if (j < kNM1) {
      const float* src = attn_w + (size_t)j * kD;
      for (int i = threadIdx.x; i < kD; i += 256) {
        int a = i / kH, h = i % kH;
        lw[a * (kH + 1) + h] = src[i];
      }
      __syncthreads();
      for (int dp = threadIdx.x; dp < kD; dp += 256) {
        int h = dp >> 4, a = dp & 15;
        dst[dp] = f2bf(lw[a * (kH + 1) + h]);
      }
    } else {
      for (int dp = threadIdx.x; dp < kD; dp += 256) dst[dp] = 0;
    }
  } else {
    int jp = j - kNP;                        // 0..383
    const float* src = nullptr;
    if (jp < 3 * kS)                src = reg_w + (size_t)jp * kK2;
    else if (jp < 3 * kS + kNC)     src = cls_w + (size_t)(jp - 3 * kS) * kK2;
    short* d0 = wcomb + (size_t)(kNP + jp) * kD;
    short* d1 = wcomb + (size_t)(kNP + 384 + jp) * kD;
    if (src) {
      for (int i = threadIdx.x; i < kK2; i += 256) {
        int half = i / kD, t = i % kD;
        int a = t / kH, h = t % kH;
        lw[(half * kAFC + a) * (kH + 1) + h] = src[i];
      }
      __syncthreads();
      for (int kp = threadIdx.x; kp < kD; kp += 256) {
        int h = kp >> 4, a = kp & 15;
        d0[kp] = f2bf(lw[a * (kH + 1) + h]);
        d1[kp] = f2bf(lw[(kAFC + a) * (kH + 1) + h]);
      }
    } else {
      for (int kp = threadIdx.x; kp < kD; kp += 256) { d0[kp] = 0; d1[kp] = 0; }
    }
  }
}

// ---------------- softmax: bf16 scores -> attn f32 out + attn bf16 padded ---
__global__ __launch_bounds__(256) void k_softmax(const short* __restrict__ scores,
                                                 const float* __restrict__ anchors,
                                                 float* __restrict__ attn_out,
                                                 short* __restrict__ attn_bf,
                                                 float* __restrict__ rp) {
  int m = blockIdx.x;           // 0..15999
  int b = m / kN;
  int i = m % kN;
  const short* srow = scores + (size_t)m * 1000;
  int tid = threadIdx.x;
  int j0 = tid * 4;
  __shared__ float red[4];
  float v[4];
  if (j0 < 1000) {
    short4 s4 = *(const short4*)(srow + j0);
    v[0] = bf2f(s4.x); v[1] = bf2f(s4.y); v[2] = bf2f(s4.z); v[3] = bf2f(s4.w);
  } else {
    v[0] = v[1] = v[2] = v[3] = -INFINITY;
  }
#pragma unroll
  for (int t = 0; t < 4; t++) if (j0 + t >= kNM1) v[t] = -INFINITY;
  float mx = fmaxf(fmaxf(v[0], v[1]), fmaxf(v[2], v[3]));
#pragma unroll
  for (int o = 32; o; o >>= 1) mx = fmaxf(mx, __shfl_down(mx, o));
  if ((tid & 63) == 0) red[tid >> 6] = mx;
  __syncthreads();
  mx = fmaxf(fmaxf(red[0], red[1]), fmaxf(red[2], red[3]));
  __syncthreads();
  float s = 0.f;
#pragma unroll
  for (int t = 0; t < 4; t++) {
    v[t] = (j0 + t < kNM1) ? __expf(v[t] - mx) : 0.f;
    s += v[t];
  }
#pragma unroll
  for (int o = 32; o; o >>= 1) s += __shfl_down(s, o);
  if ((tid & 63) == 0) red[tid >> 6] = s;
  __syncthreads();
  s = red[0] + red[1] + red[2] + red[3];
  float inv = 1.0f / s;
  float* orow = attn_out + (size_t)m * kN;
  short* brow = attn_bf + ((size_t)b * kNP + i) * kNP;
  if (j0 + 3 < i && j0 + 3 < kNM1) {
    float p0 = v[0] * inv, p1 = v[1] * inv, p2v = v[2] * inv, p3 = v[3] * inv;
    *(float4*)(orow + j0) = make_float4(p0, p1, p2v, p3);
    *(short4*)(brow + j0) = make_short4(f2bf(p0), f2bf(p1), f2bf(p2v), f2bf(p3));
  } else {
#pragma unroll
    for (int t = 0; t < 4; t++) {
      int j = j0 + t;
      if (j < kNM1) {
        int dst = j + (j >= i);
        float p = v[t] * inv;
        orow[dst] = p;
        brow[dst] = f2bf(p);
      }
    }
  }
  if (tid == 0) { orow[i] = 0.f; brow[i] = 0; }
  if (tid < kNP - kN) brow[kN + tid] = 0;           // pad cols 1000..1023
  if (tid < 3) rp[(size_t)m * kRP + 2 + tid] = anchors[(size_t)i * kRP + 2 + tid];
}

// ---------------- merged GEMM: C = baf @ wcomb^T, 256x256 tile, ring --------
// n-tiles 0-3 -> scores; tile 4 + pass0 of 5 -> p1t (LDS transpose);
// rest of 5 + tile 6 -> p2 (direct); tile 6 skips the transpose path.
__global__ __launch_bounds__(512, 2) void k_mgemm(
    const short* __restrict__ A,
    const short* __restrict__ Bt,     // wcomb [1792][2560]
    const float* __restrict__ bias,
    short* __restrict__ scores,
    short* __restrict__ p1t,
    short* __restrict__ p2) {
  extern __shared__ char dls[];                // 128 KB: 4 bufs x (A 16K + B 16K)
  constexpr int NT = kD / 32;                  // 80
  int tid = threadIdx.x, lane = tid & 63, wv = tid >> 6;
  int bid = blockIdx.x;
  int xcd = bid & 7, s = bid >> 3;             // s: 0..55
  int m0 = (xcd * 8 + (s & 7)) * 256;          // 0..16128 (M padded via clamp)
  int n0t = s >> 3;                            // 0..6
  int n0 = n0t * 256;
  int wm = (wv & 1) * 128, wn = (wv >> 1) * 64;
  f32x4 acc[8][4] = {};

  int r0  = tid >> 2;
  int r1  = (512 + tid) >> 2;
  int swzko = (((tid & 3) ^ ((tid >> 3) & 3)) * 8);   // pre-swizzled k-offset
  int ar0 = min(m0 + r0, kM - 1);
  int ar1 = min(m0 + r1, kM - 1);
  const short* gA0 = A + (size_t)ar0 * kD + swzko;
  const short* gA1 = A + (size_t)ar1 * kD + swzko;
  const short* gB0 = Bt + (size_t)(n0 + r0) * kD + swzko;
  const short* gB1 = Bt + (size_t)(n0 + r1) * kD + swzko;

  auto STAGE = [&](int tt) {
    char* buf = dls + (size_t)(tt & 3) * 32768;
    int k0 = tt * 32;
    GLOAD_LDS16(gA0 + k0, buf + wv * 1024);
    GLOAD_LDS16(gA1 + k0, buf + 8192 + wv * 1024);
    GLOAD_LDS16(gB0 + k0, buf + 16384 + wv * 1024);
    GLOAD_LDS16(gB1 + k0, buf + 24576 + wv * 1024);
  };

  int cswz = (((lane >> 4) ^ ((lane >> 1) & 3)) * 16); // swizzled read column

  STAGE(0); STAGE(1); STAGE(2);
  for (int t = 0; t < NT; t++) {
    if (t < NT - 2)       asm volatile("s_waitcnt vmcnt(8)" ::: "memory");
    else if (t == NT - 2) asm volatile("s_waitcnt vmcnt(4)" ::: "memory");
    else                  asm volatile("s_waitcnt vmcnt(0)" ::: "memory");
    __builtin_amdgcn_s_barrier();
    __builtin_amdgcn_sched_barrier(0);
    if (t + 3 < NT) STAGE(t + 3);
    const char* bufA = dls + (size_t)(t & 3) * 32768;
    const char* bufB = bufA + 16384;
    bf16x8 af[8], bg[4];
#pragma unroll
    for (int i = 0; i < 8; i++)
      af[i] = *(const bf16x8*)(bufA + (wm + i * 16 + (lane & 15)) * 64 + cswz);
#pragma unroll
    for (int j = 0; j < 4; j++)
      bg[j] = *(const bf16x8*)(bufB + (wn + j * 16 + (lane & 15)) * 64 + cswz);
    __builtin_amdgcn_s_setprio(1);
#pragma unroll
    for (int i = 0; i < 8; i++)
#pragma unroll
      for (int j = 0; j < 4; j++)
        acc[i][j] = __builtin_amdgcn_mfma_f32_16x16x32_bf16(af[i], bg[j], acc[i][j], 0, 0, 0);
    __builtin_amdgcn_s_setprio(0);
  }

  if (n0t < 4) {
    // scores region
#pragma unroll
    for (int i = 0; i < 8; i++) {
#pragma unroll
      for (int j = 0; j < 4; j++) {
#pragma unroll
        for (int r = 0; r < 4; r++) {
          int row = m0 + wm + i * 16 + (lane >> 4) * 4 + r;
          int col = n0 + wn + j * 16 + (lane & 15);
          if (row < kM && col < kNM1)
            scores[(size_t)row * 1000 + col] = f2bf(acc[i][j][r] + bias[col]);
        }
      }
    }
  } else {
    int base = n0 - 1024;              // w-space col offset: 0 / 256 / 512
    // direct p2 region: tile 6 all; tile 5 local cols >= 128 (jw >= 384)
    if (n0t >= 5) {
#pragma unroll
      for (int i = 0; i < 8; i++) {
#pragma unroll
        for (int j = 0; j < 4; j++) {
#pragma unroll
          for (int r = 0; r < 4; r++) {
            int row = m0 + wm + i * 16 + (lane >> 4) * 4 + r;
            int cl = wn + j * 16 + (lane & 15);
            int jw = base + cl;
            if (jw >= 384 && row < kM)
              p2[(size_t)row * 384 + (jw - 384)] = f2bf(acc[i][j][r]);
          }
        }
      }
    }
    // transpose region -> p1t: ONLY tiles 4 (both passes) and 5 (pass 0).
    if (n0t <= 5) {
      short* lds2 = (short*)dls;       // [128 cols][264]
      int npass = (n0t == 4) ? 2 : 1;
      for (int pass = 0; pass < npass; pass++) {
        if ((wn < 128) == (pass == 0)) {
#pragma unroll
          for (int i = 0; i < 8; i++) {
#pragma unroll
            for (int j = 0; j < 4; j++) {
#pragma unroll
              for (int r = 0; r < 4; r++) {
                int rowl = wm + i * 16 + (lane >> 4) * 4 + r;      // 0..255
                int cl = (wn + j * 16 + (lane & 15)) - pass * 128; // 0..127
                lds2[cl * 264 + rowl] = f2bf(acc[i][j][r]);
              }
            }
          }
        }
        __syncthreads();
        for (int u = tid; u < 128 * 32; u += 512) {
          int c = u >> 5, oct = u & 31;
          int jw = base + pass * 128 + c;
          int grow = m0 + oct * 8;
          if (grow < kM && jw < 384) {
            int b = grow / kN, n = grow - b * kN;
            *(bf16x8*)(p1t + ((size_t)b * 384 + jw) * kNP + n) =
                *(const bf16x8*)(lds2 + c * 264 + oct * 8);
          }
        }
        __syncthreads();
      }
    }
  }
}

// ---------------- F-GEMM: Y[b] = attn_bf[b] @ p1t[b]^T + p2 + epilogue ------
// BM=32, 512 blocks, 3-deep ring (78 KB -> 2 blocks/CU), vmcnt(4) steady.
__global__ __launch_bounds__(512, 2) void k_fgemm(
    const short* __restrict__ attn_bf,  // [16][1024][1024]
    const short* __restrict__ p1t,      // [16][384][1024]
    const short* __restrict__ p2,       // [16000][384]
    const float* __restrict__ reg_b, const float* __restrict__ cls_b,
    const float* __restrict__ anchors, float* __restrict__ rp) {
  extern __shared__ char dls[];      // 3 bufs x (A 2K + B 24K) = 78 KB
  constexpr int NT = kNP / 32;       // 32
  constexpr int BUFSZ = 26624;
  int tid = threadIdx.x, lane = tid & 63, wv = tid >> 6;
  int bid = blockIdx.x;
  int b = bid & 15, mt = bid >> 4;   // XCD = bid&7 -> b in {x, x+8}: p1t L2-hot
  int m0 = mt * 32;                  // mt 0..31
  const short* Ap = attn_bf + (size_t)b * kNP * kNP;
  const short* Bp = p1t + (size_t)b * 384 * kNP;

  int wm = (wv & 1) * 16, wn = (wv >> 1) * 96;
  f32x4 acc[6] = {};

  int ciA = tid & 127;
  int swzkoA = (((ciA & 3) ^ ((ciA >> 3) & 3)) * 8);
  int swzko  = (((tid & 3) ^ ((tid >> 3) & 3)) * 8);
  const short* gA  = Ap + (size_t)(m0 + (ciA >> 2)) * kNP + swzkoA;
  const short* gB0 = Bp + (size_t)(tid >> 2) * kNP + swzko;
  const short* gB1 = Bp + (size_t)((512 + tid) >> 2) * kNP + swzko;
  const short* gB2 = Bp + (size_t)((1024 + tid) >> 2) * kNP + swzko;

  auto STAGE = [&](int tt) {
    char* buf = dls + (size_t)(tt % 3) * BUFSZ;
    int k0 = tt * 32;
    GLOAD_LDS16(gA + k0,  buf + (wv & 1) * 1024);
    GLOAD_LDS16(gB0 + k0, buf + 2048 + wv * 1024);
    GLOAD_LDS16(gB1 + k0, buf + 10240 + wv * 1024);
    GLOAD_LDS16(gB2 + k0, buf + 18432 + wv * 1024);
  };

  int cswz = (((lane >> 4) ^ ((lane >> 1) & 3)) * 16);

  STAGE(0); STAGE(1);
  for (int t = 0; t < NT; t++) {
    if (t < NT - 1) asm volatile("s_waitcnt vmcnt(4)" ::: "memory");
    else            asm volatile("s_waitcnt vmcnt(0)" ::: "memory");
    __builtin_amdgcn_s_barrier();
    __builtin_amdgcn_sched_barrier(0);
    if (t + 2 < NT) STAGE(t + 2);
    const char* bufA = dls + (size_t)(t % 3) * BUFSZ;
    const char* bufB = bufA + 2048;
    bf16x8 af, bg[6];
    af = *(const bf16x8*)(bufA + (wm + (lane & 15)) * 64 + cswz);
#pragma unroll
    for (int j = 0; j < 6; j++)
      bg[j] = *(const bf16x8*)(bufB + (wn + j * 16 + (lane & 15)) * 64 + cswz);
    __builtin_amdgcn_s_setprio(1);
#pragma unroll
    for (int j = 0; j < 6; j++)
      acc[j] = __builtin_amdgcn_mfma_f32_16x16x32_bf16(af, bg[j], acc[j], 0, 0, 0);
    __builtin_amdgcn_s_setprio(0);
  }

#pragma unroll
  for (int j = 0; j < 6; j++) {
#pragma unroll
    for (int r = 0; r < 4; r++) {
      int n = m0 + wm + (lane >> 4) * 4 + r;            // 0..1023
      int col = wn + j * 16 + (lane & 15);              // 0..383
      if (n < kN) {
        size_t row = (size_t)b * kN + n;
        float v = acc[j][r] + bf2f(p2[row * 384 + col]);
        if (col < 3 * kS) {
          float tv = v + reg_b[col];
          if (col >= 2 * kS) tv = 1.0f / (1.0f + __expf(-tv));
          rp[row * kRP + 5 + col] = anchors[(size_t)n * kRP + 5 + col] + tv;
        } else if (col < 3 * kS + kNC) {
          rp[row * kRP + (col - 3 * kS)] = v + cls_b[col - 3 * kS];
        }
      }
    }
  }
}

extern "C" void kernel_launch(void* const* d_in, const int* in_sizes, int n_in,
                              void* d_out, int out_size, void* d_ws, size_t ws_size,
                              hipStream_t stream) {
  const float* bf      = (const float*)d_in[0];
  const float* conv_w  = (const float*)d_in[1];
  const float* conv_b  = (const float*)d_in[2];
  const int*   cut     = (const int*)d_in[3];
  const void*  mask    = d_in[4];
  const float* anchors = (const float*)d_in[5];
  const float* attn_w  = (const float*)d_in[6];
  const float* attn_b  = (const float*)d_in[7];
  const float* cls_w   = (const float*)d_in[8];
  const float* cls_b   = (const float*)d_in[9];
  const float* reg_w   = (const float*)d_in[10];
  const float* reg_b   = (const float*)d_in[11];

  float* out    = (float*)d_out;
  float* rp     = out + OFF_RP;
  float* attn_o = out + OFF_ATTN;
  float* feats  = out + OFF_FEAT;

  char*  ws      = (char*)d_ws;
  short* baf     = (short*)(ws + WB_BAF);
  short* wcomb   = (short*)(ws + WB_WCOMB);
  short* attn_bf = (short*)(ws + WB_ATTNB);
  short* scores  = (short*)(ws + WB_SCORE);
  short* p1t     = (short*)(ws + WB_P1T);
  short* p2      = (short*)(ws + WB_P2);
  int*   cnt     = (int*)(ws + WB_CNT);

  k_detect<<<160, 256, 0, stream>>>((const unsigned char*)mask, cnt);
  k_conv<<<(kB * kHW / 4 + 255) / 256, 256, 0, stream>>>(bf, conv_w, conv_b, feats);
  // gather: one block per (b,h); 2560 blocks
  k_gather<<<kB * kH, 256, 0, stream>>>(feats, cut, mask, cnt, baf);
  k_cvt_wcomb<<<kNP + 384, 256, 0, stream>>>(attn_w, reg_w, cls_w, wcomb);
  // merged GEMM: 448 blocks (8 XCD x 8 m x 7 n; m fastest within XCD stripe)
  k_mgemm<<<448, 512, 131072, stream>>>(baf, wcomb, attn_b, scores, p1t, p2);
  k_softmax<<<kM, 256, 0, stream>>>(scores, anchors, attn_o, attn_bf, rp);
  // F-GEMM: 512 blocks (16 batches x 32 m-tiles), 2 blocks/CU
  k_fgemm<<<512, 512, 79872, stream>>>(attn_bf, p1t, p2, reg_b, cls_b,
                                       anchors, rp);
}